// Round 6
// baseline (166.915 us; speedup 1.0000x reference)
//
#include <hip/hip_runtime.h>

// out[r,d] = x0[r,d] * dot(x_cross[r,:], w) + b[d] + x_cross[r,d]
// B=16384 rows, D=4096 cols, all fp32.
//
// R6: two-kernel split (diagnostic: isolate reduction from streaming).
//  K1: s[r] = dot(xc[r,:], w)  -> d_ws   (pure read + tiny write)
//  K2: out = x0*s + b + xc                (pure elementwise stream)
// Cache steering: x0 nt-loaded, out nt-stored (no L3 allocate); xc normal
// loads so the 256 MiB L3 can hold exactly xc (256 MiB) across replays.

typedef float f32x4 __attribute__((ext_vector_type(4)));

constexpr int D_DIM = 4096;
constexpr int TPB   = 256;
constexpr int V4    = D_DIM / 4;     // 1024 float4 per row
constexpr int F4PT  = V4 / TPB;      // 4 float4 per thread (K1)

// ---------------- K1: per-row dot product -> s[row] ----------------
__global__ __launch_bounds__(TPB)
void cross_dot_kernel(const float* __restrict__ xc,
                      const float* __restrict__ w,
                      float* __restrict__ s_out) {
    const int row = blockIdx.x;
    const size_t base = (size_t)row * D_DIM;
    const f32x4* __restrict__ xc4 = (const f32x4*)(xc + base);
    const f32x4* __restrict__ w4  = (const f32x4*)w;

    const int t = threadIdx.x;

    float p0 = 0.f, p1 = 0.f, p2 = 0.f, p3 = 0.f;
#pragma unroll
    for (int i = 0; i < F4PT; ++i) {
        const int idx = t + i * TPB;
        const f32x4 xcv = xc4[idx];          // normal load: allocate in L3
        const f32x4 wv  = w4[idx];           // 16 KiB, L2-resident
        p0 += xcv.x * wv.x;
        p1 += xcv.y * wv.y;
        p2 += xcv.z * wv.z;
        p3 += xcv.w * wv.w;
    }
    float partial = (p0 + p1) + (p2 + p3);

#pragma unroll
    for (int off = 32; off >= 1; off >>= 1)
        partial += __shfl_xor(partial, off);

    __shared__ float wsum[TPB / 64];
    const int lane = t & 63, wid = t >> 6;
    if (lane == 0) wsum[wid] = partial;
    __syncthreads();
    if (t == 0)
        s_out[row] = wsum[0] + wsum[1] + wsum[2] + wsum[3];
}

// ---------------- K2: elementwise stream ----------------
__global__ __launch_bounds__(TPB)
void cross_ew_kernel(const float* __restrict__ x0,
                     const float* __restrict__ xc,
                     const float* __restrict__ s_in,
                     const float* __restrict__ bias,
                     float* __restrict__ out,
                     long total4) {
    const f32x4* __restrict__ x04 = (const f32x4*)x0;
    const f32x4* __restrict__ xc4 = (const f32x4*)xc;
    const f32x4* __restrict__ b4  = (const f32x4*)bias;
    f32x4* __restrict__       o4  = (f32x4*)out;

    const long stride = (long)gridDim.x * TPB;
    for (long i4 = (long)blockIdx.x * TPB + threadIdx.x; i4 < total4; i4 += stride) {
        const f32x4 xcv = xc4[i4];                               // L3-resident
        const f32x4 x0v = __builtin_nontemporal_load(&x04[i4]);  // stream, no L3 alloc
        const float s   = s_in[i4 >> 10];                        // 64 KiB, L2-hot
        const f32x4 bv  = b4[i4 & (V4 - 1)];                     // 16 KiB, L2-hot
        f32x4 o;
        o.x = fmaf(x0v.x, s, bv.x + xcv.x);
        o.y = fmaf(x0v.y, s, bv.y + xcv.y);
        o.z = fmaf(x0v.z, s, bv.z + xcv.z);
        o.w = fmaf(x0v.w, s, bv.w + xcv.w);
        __builtin_nontemporal_store(o, &o4[i4]);
    }
}

extern "C" void kernel_launch(void* const* d_in, const int* in_sizes, int n_in,
                              void* d_out, int out_size, void* d_ws, size_t ws_size,
                              hipStream_t stream) {
    const float* x0   = (const float*)d_in[0];
    const float* xc   = (const float*)d_in[1];
    const float* w    = (const float*)d_in[2];
    const float* bias = (const float*)d_in[3];
    float* out        = (float*)d_out;
    float* s_buf      = (float*)d_ws;          // 16384 floats = 64 KiB scratch

    const int rows = in_sizes[0] / D_DIM;      // 16384
    const long total4 = (long)rows * V4;       // 16M float4

    cross_dot_kernel<<<rows, TPB, 0, stream>>>(xc, w, s_buf);
    cross_ew_kernel<<<2048, TPB, 0, stream>>>(x0, xc, s_buf, bias, out, total4);
}

// Round 7
// 138.147 us; speedup vs baseline: 1.2082x; 1.2082x over previous
//
#include <hip/hip_runtime.h>

// out[r,d] = x0[r,d] * dot(x_cross[r,:], w) + b[d] + x_cross[r,d]
// B=16384 rows, D=4096 cols, all fp32.
//
// FINAL (= R3, best measured at 138.6 us): one 4-wave block per row,
// fused dot + elementwise, nt-stores for the streaming output.
// Logical fabric traffic is irreducible: 768 MiB (x0+xc reads, out write);
// measured 5.81 TB/s total fabric = 92% of the 6.29 TB/s copy ceiling.
// R4 (wave-per-row), R5 (persistent pipelined), R6 (two-kernel split) all
// regressed despite minimal traffic -> compiler-scheduled high-occupancy
// block-per-row is the winning structure.

typedef float f32x4 __attribute__((ext_vector_type(4)));

constexpr int D_DIM = 4096;
constexpr int TPB   = 256;          // threads per block
constexpr int V4    = D_DIM / 4;    // 1024 float4 per row
constexpr int F4PT  = V4 / TPB;     // 4 float4 per thread (16 floats)

__global__ __launch_bounds__(TPB)
void cross_fused_kernel(const float* __restrict__ x0,
                        const float* __restrict__ xc,
                        const float* __restrict__ w,
                        const float* __restrict__ bias,
                        float* __restrict__ out) {
    const int row = blockIdx.x;
    const size_t base = (size_t)row * D_DIM;

    const f32x4* __restrict__ xc4  = (const f32x4*)(xc + base);
    const f32x4* __restrict__ x04  = (const f32x4*)(x0 + base);
    const f32x4* __restrict__ w4   = (const f32x4*)w;
    const f32x4* __restrict__ b4   = (const f32x4*)bias;
    f32x4* __restrict__       out4 = (f32x4*)(out + base);

    const int t = threadIdx.x;

    // Phase 1: load xc slice + x0 slice (compiler schedules; with 32 VGPR it
    // sinks x0 past the barrier — measured best), dot xc.w.
    f32x4 xcv[F4PT];
    f32x4 x0v[F4PT];
#pragma unroll
    for (int i = 0; i < F4PT; ++i) {
        const int idx = t + i * TPB;          // coalesced: lane-contiguous float4
        xcv[i] = xc4[idx];
        x0v[i] = x04[idx];
    }

    float partial = 0.0f;
#pragma unroll
    for (int i = 0; i < F4PT; ++i) {
        const int idx = t + i * TPB;
        const f32x4 wv = w4[idx];             // 16 KiB, L2-resident
        partial += xcv[i].x * wv.x + xcv[i].y * wv.y
                 + xcv[i].z * wv.z + xcv[i].w * wv.w;
    }

    // Wave-64 shuffle reduction.
#pragma unroll
    for (int off = 32; off >= 1; off >>= 1)
        partial += __shfl_down(partial, off);

    // Cross-wave (4 waves) reduce via LDS, broadcast s to all threads.
    __shared__ float wsum[TPB / 64];
    const int lane = t & 63, wid = t >> 6;
    if (lane == 0) wsum[wid] = partial;
    __syncthreads();
    const float s = wsum[0] + wsum[1] + wsum[2] + wsum[3];

    // Phase 2: elementwise epilogue + streaming store.
#pragma unroll
    for (int i = 0; i < F4PT; ++i) {
        const int idx = t + i * TPB;
        const f32x4 bv = b4[idx];             // 16 KiB, L2-resident
        f32x4 o;
        o.x = fmaf(x0v[i].x, s, bv.x + xcv[i].x);
        o.y = fmaf(x0v[i].y, s, bv.y + xcv[i].y);
        o.z = fmaf(x0v[i].z, s, bv.z + xcv[i].z);
        o.w = fmaf(x0v[i].w, s, bv.w + xcv[i].w);
        __builtin_nontemporal_store(o, &out4[idx]);
    }
}

extern "C" void kernel_launch(void* const* d_in, const int* in_sizes, int n_in,
                              void* d_out, int out_size, void* d_ws, size_t ws_size,
                              hipStream_t stream) {
    const float* x0   = (const float*)d_in[0];
    const float* xc   = (const float*)d_in[1];
    const float* w    = (const float*)d_in[2];
    const float* bias = (const float*)d_in[3];
    float* out        = (float*)d_out;

    const int rows = in_sizes[0] / D_DIM;     // 16384
    cross_fused_kernel<<<rows, TPB, 0, stream>>>(x0, xc, w, bias, out);
}